// Round 6
// baseline (1690.247 us; speedup 1.0000x reference)
//
#include <hip/hip_runtime.h>

// ---------------------------------------------------------------------------
// FCOS head on MI355X: bf16 MFMA implicit-GEMM 3x3 convs.
//   activations: padded NHWC bf16, [B][H+2][W+2][256], zero borders
//   stem weights: [s][tap][co][ci] bf16 (B^T, row-contiguous in ci)
//   pred weights: [tap][96][ci] bf16 (rows 0..79 cls, 80..83 box, 84 ctr, pad)
//
// R2: XOR chunk-swizzled LDS -> bank conflicts 5.66e7 -> 0 (verified).
// R3: vectorized epilogue via wave-private LDS transpose; level-fused grids.
// R5: tap-row A staging + exec-uniform tail slot w/ per-lane global clamp.
//     (R4 lesson: global_load_lds must be issued exec-uniformly.)
// R6: BN=256 blocks (512 thr, 8 waves of 64x64): kills n-tile A duplication;
//     A staged once per ci-chunk covering the full (R+2)-row window, serving
//     all 9 taps (A staging /3, barriers per FLOP /2, 32 MFMA per barrier
//     pair per wave). LDS 72KB -> 2 blocks/CU (16 waves). Launch fusion:
//     prepack/border/cast each a single dispatch (14 -> 7 launches).
// ---------------------------------------------------------------------------

typedef __bf16 bf16;
typedef __attribute__((ext_vector_type(8))) __bf16 bf16x8;
typedef __attribute__((ext_vector_type(4))) float f32x4;

typedef unsigned int uint32_as1 __attribute__((address_space(1)));
typedef unsigned int uint32_as3 __attribute__((address_space(3)));

__device__ __forceinline__ void gl_lds16(const bf16* g, bf16* l) {
    __builtin_amdgcn_global_load_lds(
        (const uint32_as1*)(unsigned long long)g,
        (uint32_as3*)(unsigned int)(unsigned long long)l,
        16, 0, 0);
}

struct StemTab {
    const bf16* inC[3]; const bf16* inB[3];
    bf16* outC[3]; bf16* outB[3];
    int H[3]; int lw[3]; int lhw[3];
    int xend0, xend1;
};
struct PredTab {
    const bf16* inC[3]; const bf16* inB[3];
    int H[3]; int lw[3]; int lhw[3]; int offl[3];
    int xend0, xend1;
};
struct CastTab {
    const float* in[3]; bf16* out[3];
    int H[3]; int lw[3];
    int xend0, xend1;
};
struct BZTab {
    bf16* base[3]; int H[3]; size_t bufE[3]; int ppi[3];
    int xend0, xend1;
};

// ---------------------------------------------------------------------------
// Stem conv: 128(m) x 256(n) tile, 512 threads = 8 waves of 64x64, dual-path
// via z, fused levels. Per ci-chunk (64): stage full A window (R+2 rows) once,
// then 9 taps x { stage B(256x64), barrier, 32 MFMA/wave, barrier }.
// ---------------------------------------------------------------------------
__global__ __launch_bounds__(512, 4) void stem_conv_kernel(
    StemTab tab, const bf16* __restrict__ Wc, const bf16* __restrict__ Wb,
    const float* __restrict__ bc, const float* __restrict__ bb)
{
    const int bx = blockIdx.x;
    const int l  = (bx >= tab.xend0) + (bx >= tab.xend1);
    const int start = (l == 0) ? 0 : (l == 1 ? tab.xend0 : tab.xend1);
    const int local = bx - start;
    const int H = tab.H[l], lw = tab.lw[l], lhw = tab.lhw[l];

    const bf16* A; bf16* O; const bf16* BT; const float* bias;
    if (blockIdx.z == 0) { A = tab.inC[l]; O = tab.outC[l]; BT = Wc; bias = bc; }
    else                 { A = tab.inB[l]; O = tab.outB[l]; BT = Wb; bias = bb; }

    const int W   = 1 << lw;
    const int Wp  = W + 2;
    const int HW  = 1 << lhw;
    const int tid = threadIdx.x;
    const int m_base = local * 128;
    const int b   = m_base >> lhw;
    const int y0  = (m_base & (HW - 1)) >> lw;     // window = rows y0..y0+R+1
    const int ibase = b * (H + 2) * Wp * 256;

    // LDS: A = 320 px rows x 64 ch (20480 el), B = 256 co x 64 ci (16384 el)
    __shared__ __align__(16) bf16 Sh[36864];
    bf16* Als = Sh;
    bf16* Bls = Sh + 20480;

    const int rbase = tid >> 3;                    // 0..63
    const int ch8   = (((tid & 7) ^ (rbase & 7)) << 3);
    const int npx   = ((128 >> lw) + 2) * Wp;      // 264 / 204 / 180
    const int Wp256 = Wp * 256;
    const int ag0   = ibase + y0 * Wp256 + rbase * 256 + ch8;
    int aoffs[5];                                  // exec-uniform; clamp OOW lanes
#pragma unroll
    for (int i = 0; i < 5; ++i)
        aoffs[i] = (i * 64 + rbase < npx) ? i * 16384 : 0;
    int bg[4];
#pragma unroll
    for (int i = 0; i < 4; ++i)
        bg[i] = (i * 64 + rbase) * 256 + ch8;

    f32x4 acc[4][4];
#pragma unroll
    for (int i = 0; i < 4; ++i)
#pragma unroll
        for (int j = 0; j < 4; ++j)
            acc[i][j] = (f32x4)(0.0f);

    const int lane = tid & 63;
    const int wv   = tid >> 6;                     // 0..7
    const int wm   = (wv & 1) * 64;
    const int wn   = (wv >> 1) * 64;
    const int l16  = lane & 15;
    const int quad = lane >> 4;
    // A px row for output m, tap(dy,dx): m + 2*(m>>lw) + dy*Wp + dx
    int pb[4];
#pragma unroll
    for (int i = 0; i < 4; ++i) {
        const int mm = wm + i * 16;
        pb[i] = mm + l16 + ((mm >> lw) << 1);
    }
    const int bRow = (wn + l16) * 64;
    const int bsw  = l16 & 7;
    bf16* lA = Als + tid * 8;
    bf16* lB = Bls + tid * 8;

    for (int cq = 0; cq < 4; ++cq) {
        const int c0 = cq << 6;
#pragma unroll
        for (int i = 0; i < 5; ++i)
            gl_lds16(A + ag0 + c0 + aoffs[i], lA + i * 4096);
        for (int dy = 0; dy < 3; ++dy) {
            for (int dx = 0; dx < 3; ++dx) {
                const int boff = ((dy * 3 + dx) << 16) + c0;
#pragma unroll
                for (int i = 0; i < 4; ++i)
                    gl_lds16(BT + bg[i] + boff, lB + i * 4096);
                __syncthreads();
                const int rb0 = dy * Wp + dx;
#pragma unroll
                for (int ks = 0; ks < 2; ++ks) {
                    const int qk = quad + ks * 4;
                    bf16x8 af[4], bfv[4];
#pragma unroll
                    for (int i = 0; i < 4; ++i) {
                        const int rr = pb[i] + rb0;
                        af[i] = *(const bf16x8*)(Als + (rr << 6) +
                                                 ((qk ^ (rr & 7)) << 3));
                    }
#pragma unroll
                    for (int j = 0; j < 4; ++j)
                        bfv[j] = *(const bf16x8*)(Bls + bRow + j * 1024 +
                                                  ((qk ^ bsw) << 3));
#pragma unroll
                    for (int i = 0; i < 4; ++i)
#pragma unroll
                        for (int j = 0; j < 4; ++j)
                            acc[i][j] = __builtin_amdgcn_mfma_f32_16x16x32_bf16(
                                af[i], bfv[j], acc[i][j], 0, 0, 0);
                }
                __syncthreads();
            }
        }
    }

    // ---- epilogue: bias+relu+cvt -> wave-private swizzled T -> 16B stores
    float bv[4];
#pragma unroll
    for (int j = 0; j < 4; ++j) bv[j] = bias[wn + j * 16 + l16];
    bf16* Tw = Sh + wv * 4096;                     // 64x64 bf16, chunk-swizzled
#pragma unroll
    for (int i = 0; i < 4; ++i)
#pragma unroll
        for (int r = 0; r < 4; ++r) {
            const int row = i * 16 + quad * 4 + r;
#pragma unroll
            for (int j = 0; j < 4; ++j) {
                float v = acc[i][j][r] + bv[j];
                v = v > 0.0f ? v : 0.0f;
                const int sc = (((j * 2 + (l16 >> 3)) ^ (row & 7)) << 3) + (l16 & 7);
                Tw[row * 64 + sc] = (bf16)v;
            }
        }
    __syncthreads();
    const int rgrp = lane >> 3, cc = lane & 7;
#pragma unroll
    for (int p = 0; p < 8; ++p) {
        const int row = p * 8 + rgrp;
        bf16x8 vv = *(const bf16x8*)(Tw + row * 64 + ((cc ^ (row & 7)) << 3));
        const int ml = wm + row;
        const int y  = y0 + (ml >> lw);
        const int x  = ml & (W - 1);
        *(bf16x8*)(O + ibase + ((y + 1) * Wp + (x + 1)) * 256 + wn + cc * 8) = vv;
    }
}

// ---------------------------------------------------------------------------
// Fused prediction conv (cls 80 cols from cls-feat + box/ctr 5 cols from
// box-feat). M-tile 128; writes fp32 straight into d_out (B,5376,85).
// ---------------------------------------------------------------------------
__global__ __launch_bounds__(256) void pred_conv_kernel(
    PredTab tab, const bf16* __restrict__ BT, const float* __restrict__ bias,
    float* __restrict__ out)
{
    const int bx = blockIdx.x;
    const int l  = (bx >= tab.xend0) + (bx >= tab.xend1);
    const int start = (l == 0) ? 0 : (l == 1 ? tab.xend0 : tab.xend1);
    const int mt = bx - start;
    const int H = tab.H[l], lw = tab.lw[l], lhw = tab.lhw[l], off_l = tab.offl[l];
    const bf16* Ac = tab.inC[l];
    const bf16* Ab = tab.inB[l];

    const int W   = 1 << lw;
    const int Wp  = W + 2;
    const int HW  = 1 << lhw;
    const int tid = threadIdx.x;
    const int m_base = mt * 128;
    const int b   = m_base >> lhw;
    const int mi  = m_base & (HW - 1);
    const int y0  = mi >> lw;
    const int ibase = b * (H + 2) * Wp * 256;

    __shared__ __align__(16) bf16 Sh[(128 + 128 + 96) * 64];  // Ac|Ab|B

    const int ch8   = (((tid & 7) ^ ((tid >> 3) & 7)) << 3);
    const int rbase = tid >> 3;
    int ag[4], bg[3];
#pragma unroll
    for (int i = 0; i < 4; ++i) {
        int row = i * 32 + rbase;
        int y = y0 + (row >> lw);
        int x = row & (W - 1);
        ag[i] = ibase + (y * Wp + x) * 256 + ch8;
    }
#pragma unroll
    for (int i = 0; i < 3; ++i)
        bg[i] = (i * 32 + rbase) * 256 + ch8;

    f32x4 accC[2][5], accB[2];
#pragma unroll
    for (int i = 0; i < 2; ++i) {
#pragma unroll
        for (int j = 0; j < 5; ++j) accC[i][j] = (f32x4)(0.0f);
        accB[i] = (f32x4)(0.0f);
    }

    const int lane = tid & 63;
    const int wv   = tid >> 6;
    const int l16  = lane & 15;
    const int quad = lane >> 4;
    const int xsw  = l16 & 7;
    const int aRow = (wv * 32 + l16) * 64;
    bf16* lS = Sh + tid * 8;

    for (int kc = 0; kc < 36; ++kc) {
        const int t  = kc >> 2;
        const int dy = t / 3;
        const int dx = t - dy * 3;
        const int c0 = (kc & 3) << 6;
        const int aoff = (dy * Wp + dx) * 256 + c0;
        const int boff = t * 24576 + c0;          // t*96*256
#pragma unroll
        for (int i = 0; i < 4; ++i)
            gl_lds16(Ac + ag[i] + aoff, lS + i * 2048);
#pragma unroll
        for (int i = 0; i < 4; ++i)
            gl_lds16(Ab + ag[i] + aoff, lS + (4 + i) * 2048);
#pragma unroll
        for (int i = 0; i < 3; ++i)
            gl_lds16(BT + bg[i] + boff, lS + (8 + i) * 2048);
        __syncthreads();
#pragma unroll
        for (int ks = 0; ks < 2; ++ks) {
            const int cO = (((quad + ks * 4) ^ xsw) << 3);
            bf16x8 afc[2], afb[2], bfv[5], bfb;
#pragma unroll
            for (int i = 0; i < 2; ++i) {
                afc[i] = *(const bf16x8*)(Sh + aRow + i * 1024 + cO);
                afb[i] = *(const bf16x8*)(Sh + 8192 + aRow + i * 1024 + cO);
            }
#pragma unroll
            for (int j = 0; j < 5; ++j)
                bfv[j] = *(const bf16x8*)(Sh + 16384 + (j * 16 + l16) * 64 + cO);
            bfb = *(const bf16x8*)(Sh + 16384 + (80 + l16) * 64 + cO);
#pragma unroll
            for (int i = 0; i < 2; ++i) {
#pragma unroll
                for (int j = 0; j < 5; ++j)
                    accC[i][j] = __builtin_amdgcn_mfma_f32_16x16x32_bf16(
                        afc[i], bfv[j], accC[i][j], 0, 0, 0);
                accB[i] = __builtin_amdgcn_mfma_f32_16x16x32_bf16(
                    afb[i], bfb, accB[i], 0, 0, 0);
            }
        }
        __syncthreads();
    }

#pragma unroll
    for (int i = 0; i < 2; ++i) {
#pragma unroll
        for (int r = 0; r < 4; ++r) {
            const int ml  = wv * 32 + i * 16 + quad * 4 + r;
            const int pos = mi + ml;
            const int ob  = (b * 5376 + off_l + pos) * 85;
#pragma unroll
            for (int j = 0; j < 5; ++j)
                out[ob + j * 16 + l16] = accC[i][j][r] + bias[j * 16 + l16];
            if (l16 < 5)
                out[ob + 80 + l16] = accB[i][r] + bias[80 + l16];
        }
    }
}

// ---------------------------------------------------------------------------
// Init: fp32 NCHW -> padded NHWC bf16 via LDS transpose (coalesced both sides)
// One dispatch for all levels; job = b*H + y (one output row).
// ---------------------------------------------------------------------------
__global__ __launch_bounds__(256) void cast_pad_kernel(CastTab tb)
{
    const int bx = blockIdx.x;
    const int l  = (bx >= tb.xend0) + (bx >= tb.xend1);
    const int start = (l == 0) ? 0 : (l == 1 ? tb.xend0 : tb.xend1);
    const int job = bx - start;
    const int H = tb.H[l], lw = tb.lw[l];
    const int W = 1 << lw, Wp = W + 2;
    const int b = job >> lw;               // H == W for all levels
    const int y = job & (W - 1);
    const float* in = tb.in[l] + ((size_t)(b * 256) * H + y) * W;
    bf16* out = tb.out[l] + ((size_t)(b * (H + 2) + y + 1) * Wp + 1) * 256;
    const int tid = threadIdx.x;
    __shared__ bf16 L[16384];              // [x][c], chunk-swizzled by x&31
    const int cpp = 256 >> lw;             // c rows per pass
    const int x = tid & (W - 1);
    const int cb0 = tid >> lw;
    for (int p = 0; p < W; ++p) {
        const int c = p * cpp + cb0;
        float v = in[(size_t)c * H * W + x];
        L[x * 256 + ((((c >> 3) ^ (x & 31))) << 3) + (c & 7)] = (bf16)v;
    }
    __syncthreads();
    const int wpass = W >> 3;
    for (int q = 0; q < wpass; ++q) {
        const int id = q * 256 + tid;
        const int xo = id >> 5;
        const int k  = id & 31;
        bf16x8 vv = *(const bf16x8*)(L + xo * 256 + ((k ^ (xo & 31)) << 3));
        *(bf16x8*)(out + xo * 256 + k * 8) = vv;
    }
}

// zero borders of 5 contiguous padded buffers, all levels in one dispatch
__global__ void border_zero_kernel(BZTab tb)
{
    const int bx = blockIdx.x;
    const int l  = (bx >= tb.xend0) + (bx >= tb.xend1);
    const int start = (l == 0) ? 0 : (l == 1 ? tb.xend0 : tb.xend1);
    const int i   = bx - start;
    const int buf = blockIdx.y;
    const int c   = threadIdx.x;
    const int H = tb.H[l];
    const int ppi = tb.ppi[l];
    const int img = i / ppi;
    const int p   = i - img * ppi;
    const int Wp  = H + 2, Hp = H + 2;
    int y, xp;
    if (p < Wp)            { y = 0;      xp = p; }
    else if (p < 2 * Wp)   { y = Hp - 1; xp = p - Wp; }
    else { int q = p - 2 * Wp; y = 1 + (q >> 1); xp = (q & 1) ? (Wp - 1) : 0; }
    tb.base[l][buf * tb.bufE[l] + ((size_t)(img * Hp + y) * Wp + xp) * 256 + c]
        = (bf16)0.0f;
}

// all weight prepacks in one dispatch:
//  [0,9216) stem cls, [9216,18432) stem box, [18432,19296) pred [t][96][256]
__global__ void prepack_kernel(const float* __restrict__ scw,
                               const float* __restrict__ sbw,
                               const float* __restrict__ pcw,
                               const float* __restrict__ pbw,
                               const float* __restrict__ prw,
                               const float* __restrict__ pcb,
                               const float* __restrict__ pbb,
                               const float* __restrict__ prb,
                               bf16* __restrict__ wc, bf16* __restrict__ wb,
                               bf16* __restrict__ pT, float* __restrict__ pB)
{
    const int ci = threadIdx.x;
    int g = blockIdx.x;
    if (g < 18432) {
        const float* w = (g < 9216) ? scw : sbw;
        bf16* o        = (g < 9216) ? wc  : wb;
        if (g >= 9216) g -= 9216;
        const int co = g & 255;
        const int st = g >> 8;
        const int s  = st / 9;
        const int t  = st - s * 9;
        o[(size_t)g * 256 + ci] = (bf16)w[(((s * 256 + co) * 256 + ci) * 9) + t];
    } else {
        g -= 18432;
        const int t  = g / 96;
        const int co = g - t * 96;
        float v = 0.0f;
        if (co < 80)       v = pcw[((co * 256 + ci) * 9) + t];
        else if (co < 84)  v = pbw[(((co - 80) * 256 + ci) * 9) + t];
        else if (co == 84) v = prw[(ci * 9) + t];
        pT[(size_t)g * 256 + ci] = (bf16)v;
        if (g == 0 && ci < 96) {
            float bvv = 0.0f;
            if (ci < 80)       bvv = pcb[ci];
            else if (ci < 84)  bvv = pbb[ci - 80];
            else if (ci == 84) bvv = prb[0];
            pB[ci] = bvv;
        }
    }
}

// ---------------------------------------------------------------------------
extern "C" void kernel_launch(void* const* d_in, const int* in_sizes, int n_in,
                              void* d_out, int out_size, void* d_ws, size_t ws_size,
                              hipStream_t stream)
{
    (void)in_sizes; (void)n_in; (void)out_size;
    const float* feat[3] = {(const float*)d_in[0], (const float*)d_in[1],
                            (const float*)d_in[2]};
    const float* scw = (const float*)d_in[3];
    const float* scb = (const float*)d_in[4];
    const float* sbw = (const float*)d_in[5];
    const float* sbb = (const float*)d_in[6];
    const float* pcw = (const float*)d_in[7];
    const float* pcb = (const float*)d_in[8];
    const float* pbw = (const float*)d_in[9];
    const float* pbb = (const float*)d_in[10];
    const float* prw = (const float*)d_in[11];
    const float* prb = (const float*)d_in[12];
    float* out = (float*)d_out;

    const int Hs[3]   = {64, 32, 16};
    const int lws[3]  = {6, 5, 4};
    const int lhws[3] = {12, 10, 8};
    const int offl[3] = {0, 4096, 5120};
    const int mtiles[3] = {512, 128, 32};          // M/128 per level
    size_t bufB[3];
    for (int l = 0; l < 3; ++l)
        bufB[l] = (size_t)16 * (Hs[l] + 2) * (Hs[l] + 2) * 256 * 2;

    const size_t WSTEM = (size_t)4 * 9 * 256 * 256 * 2;
    const size_t WPRED = (size_t)9 * 96 * 256 * 2;
    const size_t FULL   = 5 * (bufB[0] + bufB[1] + bufB[2]) + 2 * WSTEM + WPRED + 384;
    const size_t SHARED = 5 * bufB[0] + 2 * WSTEM + WPRED + 384;
    if (ws_size < SHARED) return;
    const bool fused = ws_size >= FULL;

    char* ws = (char*)d_ws;
    bf16* act[3][5];
    size_t off = 0;
    if (fused) {
        for (int l = 0; l < 3; ++l)
            for (int k = 0; k < 5; ++k) { act[l][k] = (bf16*)(ws + off); off += bufB[l]; }
    } else {
        for (int k = 0; k < 5; ++k)
            for (int l = 0; l < 3; ++l) act[l][k] = (bf16*)(ws + (size_t)k * bufB[0]);
        off = 5 * bufB[0];
    }
    bf16*  wbTc = (bf16*)(ws + off); off += WSTEM;
    bf16*  wbTb = (bf16*)(ws + off); off += WSTEM;
    bf16*  pT   = (bf16*)(ws + off); off += WPRED;
    float* pB   = (float*)(ws + off);

    prepack_kernel<<<dim3(19296), 256, 0, stream>>>(scw, sbw, pcw, pbw, prw,
                                                    pcb, pbb, prb,
                                                    wbTc, wbTb, pT, pB);

    auto make_stem_tab = [&](int s, int nlev, const int* levs) {
        StemTab tb{};
        for (int i = 0; i < nlev; ++i) {
            int l = levs[i];
            tb.inC[i]  = (s == 0) ? act[l][0] : ((s & 1) ? act[l][1] : act[l][2]);
            tb.inB[i]  = (s == 0) ? act[l][0] : ((s & 1) ? act[l][3] : act[l][4]);
            tb.outC[i] = (s & 1) ? act[l][2] : act[l][1];
            tb.outB[i] = (s & 1) ? act[l][4] : act[l][3];
            tb.H[i] = Hs[l]; tb.lw[i] = lws[l]; tb.lhw[i] = lhws[l];
        }
        return tb;
    };

    if (fused) {
        // border-zero: one dispatch, all levels x 5 bufs
        BZTab bz{};
        int bpx[3];
        for (int l = 0; l < 3; ++l) {
            bz.base[l] = act[l][0]; bz.H[l] = Hs[l]; bz.bufE[l] = bufB[l] / 2;
            bpx[l] = 2 * (Hs[l] + 2) + 2 * Hs[l];
            bz.ppi[l] = bpx[l];
        }
        bz.xend0 = 16 * bpx[0]; bz.xend1 = bz.xend0 + 16 * bpx[1];
        const int bztot = bz.xend1 + 16 * bpx[2];
        border_zero_kernel<<<dim3(bztot, 5), 256, 0, stream>>>(bz);

        // cast: one dispatch, all levels
        CastTab ct{};
        for (int l = 0; l < 3; ++l) {
            ct.in[l] = feat[l]; ct.out[l] = act[l][0];
            ct.H[l] = Hs[l]; ct.lw[l] = lws[l];
        }
        ct.xend0 = 16 * Hs[0]; ct.xend1 = ct.xend0 + 16 * Hs[1];
        cast_pad_kernel<<<dim3(ct.xend1 + 16 * Hs[2]), 256, 0, stream>>>(ct);

        const int levs[3] = {0, 1, 2};
        const int tx0 = mtiles[0], tx1 = mtiles[1], tx2 = mtiles[2];
        for (int s = 0; s < 4; ++s) {
            StemTab tb = make_stem_tab(s, 3, levs);
            tb.xend0 = tx0; tb.xend1 = tx0 + tx1;
            stem_conv_kernel<<<dim3(tx0 + tx1 + tx2, 1, 2), 512, 0, stream>>>(
                tb, wbTc + (size_t)s * 589824, wbTb + (size_t)s * 589824,
                scb + s * 256, sbb + s * 256);
        }
        PredTab pt{};
        for (int l = 0; l < 3; ++l) {
            pt.inC[l] = act[l][2]; pt.inB[l] = act[l][4];
            pt.H[l] = Hs[l]; pt.lw[l] = lws[l]; pt.lhw[l] = lhws[l]; pt.offl[l] = offl[l];
        }
        pt.xend0 = mtiles[0]; pt.xend1 = mtiles[0] + mtiles[1];
        pred_conv_kernel<<<dim3(mtiles[0] + mtiles[1] + mtiles[2]), 256, 0, stream>>>(
            pt, pT, pB, out);
    } else {
        for (int l = 0; l < 3; ++l) {
            const int bpx = 2 * (Hs[l] + 2) + 2 * Hs[l];
            BZTab bz{};
            bz.base[0] = act[l][0]; bz.H[0] = Hs[l]; bz.bufE[0] = bufB[0] / 2;
            bz.ppi[0] = bpx; bz.xend0 = 16 * bpx; bz.xend1 = 16 * bpx;
            border_zero_kernel<<<dim3(16 * bpx, 5), 256, 0, stream>>>(bz);
            CastTab ct{};
            ct.in[0] = feat[l]; ct.out[0] = act[l][0];
            ct.H[0] = Hs[l]; ct.lw[0] = lws[l];
            ct.xend0 = 16 * Hs[l]; ct.xend1 = 16 * Hs[l];
            cast_pad_kernel<<<dim3(16 * Hs[l]), 256, 0, stream>>>(ct);

            const int levs[1] = {l};
            for (int s = 0; s < 4; ++s) {
                StemTab tb = make_stem_tab(s, 1, levs);
                tb.xend0 = mtiles[l]; tb.xend1 = mtiles[l];
                stem_conv_kernel<<<dim3(mtiles[l], 1, 2), 512, 0, stream>>>(
                    tb, wbTc + (size_t)s * 589824, wbTb + (size_t)s * 589824,
                    scb + s * 256, sbb + s * 256);
            }
            PredTab pt{};
            pt.inC[0] = act[l][2]; pt.inB[0] = act[l][4];
            pt.H[0] = Hs[l]; pt.lw[0] = lws[l]; pt.lhw[0] = lhws[l]; pt.offl[0] = offl[l];
            pt.xend0 = mtiles[l]; pt.xend1 = mtiles[l];
            pred_conv_kernel<<<dim3(mtiles[l]), 256, 0, stream>>>(pt, pT, pB, out);
        }
    }
}

// Round 7
// 1002.125 us; speedup vs baseline: 1.6867x; 1.6867x over previous
//
#include <hip/hip_runtime.h>

// ---------------------------------------------------------------------------
// FCOS head on MI355X: bf16 MFMA implicit-GEMM 3x3 convs.
//   activations: padded NHWC bf16, [B][H+2][W+2][256], zero borders
//   stem weights: [s][tap][co][ci] bf16 (B^T, row-contiguous in ci)
//   pred weights: [tap][96][ci] bf16 (rows 0..79 cls, 80..83 box, 84 ctr, pad)
//
// R2: XOR chunk-swizzled LDS -> bank conflicts 5.66e7 -> 0 (verified).
// R3: vectorized epilogue via wave-private LDS transpose; level-fused grids.
// R5: tap-row A staging + exec-uniform tail slot w/ per-lane global clamp
//     (global_load_lds must be issued exec-uniformly — R4 crash).
//     Stem = 128x128 tile, 256 thr, 4 blocks/CU: 192 us/dispatch, 1057 TF.
// R6: BN=256/512-thr variant REGRESSED 2x (L2 thrash: FETCH 276->424 MB,
//     WRITE 86->260 MB, MfmaUtil 47->23). Reverted. Kept launch fusion
//     (single prepack / border / cast dispatches), which R6 validated.
// ---------------------------------------------------------------------------

typedef __bf16 bf16;
typedef __attribute__((ext_vector_type(8))) __bf16 bf16x8;
typedef __attribute__((ext_vector_type(4))) float f32x4;

typedef unsigned int uint32_as1 __attribute__((address_space(1)));
typedef unsigned int uint32_as3 __attribute__((address_space(3)));

__device__ __forceinline__ void gl_lds16(const bf16* g, bf16* l) {
    __builtin_amdgcn_global_load_lds(
        (const uint32_as1*)(unsigned long long)g,
        (uint32_as3*)(unsigned int)(unsigned long long)l,
        16, 0, 0);
}

struct StemTab {
    const bf16* inC[3]; const bf16* inB[3];
    bf16* outC[3]; bf16* outB[3];
    int H[3]; int lw[3]; int lhw[3];
    int xend0, xend1;
};
struct PredTab {
    const bf16* inC[3]; const bf16* inB[3];
    int H[3]; int lw[3]; int lhw[3]; int offl[3];
    int xend0, xend1;
};
struct CastTab {
    const float* in[3]; bf16* out[3];
    int H[3]; int lw[3];
    int xend0, xend1;
};
struct BZTab {
    bf16* base[3]; int H[3]; size_t bufE[3]; int ppi[3];
    int xend0, xend1;
};

// ---------------------------------------------------------------------------
// Stem conv (R5): 128x128 tile, 4 waves (2x2 of 64x64), dual-path via z,
// fused levels. K-loop: dy(3) x cq(4) x dx(3); A staged once per (dy,cq).
// ---------------------------------------------------------------------------
__global__ __launch_bounds__(256) void stem_conv_kernel(
    StemTab tab, const bf16* __restrict__ Wc, const bf16* __restrict__ Wb,
    const float* __restrict__ bc, const float* __restrict__ bb)
{
    const int bx = blockIdx.x;
    const int l  = (bx >= tab.xend0) + (bx >= tab.xend1);
    const int start = (l == 0) ? 0 : (l == 1 ? tab.xend0 : tab.xend1);
    const int local = bx - start;
    const int H = tab.H[l], lw = tab.lw[l], lhw = tab.lhw[l];

    const bf16* A; bf16* O; const bf16* BT; const float* bias;
    if (blockIdx.z == 0) { A = tab.inC[l]; O = tab.outC[l]; BT = Wc; bias = bc; }
    else                 { A = tab.inB[l]; O = tab.outB[l]; BT = Wb; bias = bb; }

    const int W   = 1 << lw;
    const int Wp  = W + 2;
    const int HW  = 1 << lhw;
    const int tid = threadIdx.x;
    const int m_base = (local >> 1) * 128;
    const int n0     = (local & 1) * 128;
    const int b   = m_base >> lhw;
    const int y0  = (m_base & (HW - 1)) >> lw;     // tile = R image rows
    const int ibase = b * (H + 2) * Wp * 256;

    // LDS: A = 160 px rows x 64ch (10240 elems), B = 128 co rows x 64 (8192)
    __shared__ __align__(16) bf16 Sh[18432];
    bf16* Als = Sh;
    bf16* Bls = Sh + 10240;

    const int ch8   = (((tid & 7) ^ ((tid >> 3) & 7)) << 3);
    const int rbase = tid >> 3;
    const int Wp256 = Wp * 256;
    const int npx   = (128 >> lw) * Wp;            // window px: 132/136/144
    // tail slot: exec-uniform issue; clamp OOW lanes' global addr into window
    const int toff  = (128 + rbase < npx) ? 4 * 8192 : 0;
    const int ag0   = ibase + rbase * 256 + ch8;
    int bg[4];
#pragma unroll
    for (int i = 0; i < 4; ++i)
        bg[i] = (n0 + i * 32 + rbase) * 256 + ch8;

    f32x4 acc[4][4];
#pragma unroll
    for (int i = 0; i < 4; ++i)
#pragma unroll
        for (int j = 0; j < 4; ++j)
            acc[i][j] = (f32x4)(0.0f);

    const int lane = tid & 63;
    const int wv   = tid >> 6;
    const int wm   = (wv & 1) * 64;
    const int wn   = (wv >> 1) * 64;
    const int l16  = lane & 15;
    const int quad = lane >> 4;
    // A fragment px-row base per i (excl dx): p(m) = m + 2*(m>>lw) + dx
    int pb[4];
#pragma unroll
    for (int i = 0; i < 4; ++i) {
        const int mm = wm + i * 16;
        pb[i] = mm + ((mm >> lw) << 1) + l16;
    }
    const int bRow = (wn + l16) * 64;
    const int bsw  = l16 & 7;
    bf16* lA = Als + tid * 8;
    bf16* lB = Bls + tid * 8;

    for (int dy = 0; dy < 3; ++dy) {
        const int abase = ag0 + (y0 + dy) * Wp256;
        for (int cq = 0; cq < 4; ++cq) {
            const int c0 = cq << 6;
            // ---- stage A window: R*(W+2) px, contiguous in global ----
#pragma unroll
            for (int i = 0; i < 4; ++i)
                gl_lds16(A + abase + c0 + i * 8192, lA + i * 2048);
            gl_lds16(A + abase + c0 + toff, lA + 4 * 2048);
            for (int dx = 0; dx < 3; ++dx) {
                const int boff = (dy * 3 + dx) * 65536 + c0;
#pragma unroll
                for (int i = 0; i < 4; ++i)
                    gl_lds16(BT + bg[i] + boff, lB + i * 2048);
                __syncthreads();
                int rowi[4];
#pragma unroll
                for (int i = 0; i < 4; ++i) rowi[i] = pb[i] + dx;
#pragma unroll
                for (int ks = 0; ks < 2; ++ks) {
                    const int qk = quad + ks * 4;
                    bf16x8 af[4], bfv[4];
#pragma unroll
                    for (int i = 0; i < 4; ++i)
                        af[i] = *(const bf16x8*)(Als + (rowi[i] << 6) +
                                                 ((qk ^ (rowi[i] & 7)) << 3));
#pragma unroll
                    for (int j = 0; j < 4; ++j)
                        bfv[j] = *(const bf16x8*)(Bls + bRow + j * 1024 +
                                                  ((qk ^ bsw) << 3));
#pragma unroll
                    for (int i = 0; i < 4; ++i)
#pragma unroll
                        for (int j = 0; j < 4; ++j)
                            acc[i][j] = __builtin_amdgcn_mfma_f32_16x16x32_bf16(
                                af[i], bfv[j], acc[i][j], 0, 0, 0);
                }
                __syncthreads();
            }
        }
    }

    // ---- epilogue: bias+relu+cvt -> wave-private swizzled T -> 16B stores
    float bv[4];
#pragma unroll
    for (int j = 0; j < 4; ++j) bv[j] = bias[n0 + wn + j * 16 + l16];
    bf16* Tw = Sh + wv * 4096;                    // 64x64 bf16, chunk-swizzled
#pragma unroll
    for (int i = 0; i < 4; ++i)
#pragma unroll
        for (int r = 0; r < 4; ++r) {
            const int row = i * 16 + quad * 4 + r;
#pragma unroll
            for (int j = 0; j < 4; ++j) {
                float v = acc[i][j][r] + bv[j];
                v = v > 0.0f ? v : 0.0f;
                const int sc = (((j * 2 + (l16 >> 3)) ^ (row & 7)) << 3) + (l16 & 7);
                Tw[row * 64 + sc] = (bf16)v;
            }
        }
    __syncthreads();
    const int rgrp = lane >> 3, cc = lane & 7;
#pragma unroll
    for (int p = 0; p < 8; ++p) {
        const int row = p * 8 + rgrp;
        bf16x8 vv = *(const bf16x8*)(Tw + row * 64 + ((cc ^ (row & 7)) << 3));
        const int ml = wm + row;
        const int y  = y0 + (ml >> lw);
        const int x  = ml & (W - 1);
        *(bf16x8*)(O + ibase + ((y + 1) * Wp + (x + 1)) * 256 + n0 + wn + cc * 8) = vv;
    }
}

// ---------------------------------------------------------------------------
// Fused prediction conv (cls 80 cols from cls-feat + box/ctr 5 cols from
// box-feat). M-tile 128; writes fp32 straight into d_out (B,5376,85).
// ---------------------------------------------------------------------------
__global__ __launch_bounds__(256) void pred_conv_kernel(
    PredTab tab, const bf16* __restrict__ BT, const float* __restrict__ bias,
    float* __restrict__ out)
{
    const int bx = blockIdx.x;
    const int l  = (bx >= tab.xend0) + (bx >= tab.xend1);
    const int start = (l == 0) ? 0 : (l == 1 ? tab.xend0 : tab.xend1);
    const int mt = bx - start;
    const int H = tab.H[l], lw = tab.lw[l], lhw = tab.lhw[l], off_l = tab.offl[l];
    const bf16* Ac = tab.inC[l];
    const bf16* Ab = tab.inB[l];

    const int W   = 1 << lw;
    const int Wp  = W + 2;
    const int HW  = 1 << lhw;
    const int tid = threadIdx.x;
    const int m_base = mt * 128;
    const int b   = m_base >> lhw;
    const int mi  = m_base & (HW - 1);
    const int y0  = mi >> lw;
    const int ibase = b * (H + 2) * Wp * 256;

    __shared__ __align__(16) bf16 Sh[(128 + 128 + 96) * 64];  // Ac|Ab|B

    const int ch8   = (((tid & 7) ^ ((tid >> 3) & 7)) << 3);
    const int rbase = tid >> 3;
    int ag[4], bg[3];
#pragma unroll
    for (int i = 0; i < 4; ++i) {
        int row = i * 32 + rbase;
        int y = y0 + (row >> lw);
        int x = row & (W - 1);
        ag[i] = ibase + (y * Wp + x) * 256 + ch8;
    }
#pragma unroll
    for (int i = 0; i < 3; ++i)
        bg[i] = (i * 32 + rbase) * 256 + ch8;

    f32x4 accC[2][5], accB[2];
#pragma unroll
    for (int i = 0; i < 2; ++i) {
#pragma unroll
        for (int j = 0; j < 5; ++j) accC[i][j] = (f32x4)(0.0f);
        accB[i] = (f32x4)(0.0f);
    }

    const int lane = tid & 63;
    const int wv   = tid >> 6;
    const int l16  = lane & 15;
    const int quad = lane >> 4;
    const int xsw  = l16 & 7;
    const int aRow = (wv * 32 + l16) * 64;
    bf16* lS = Sh + tid * 8;

    for (int kc = 0; kc < 36; ++kc) {
        const int t  = kc >> 2;
        const int dy = t / 3;
        const int dx = t - dy * 3;
        const int c0 = (kc & 3) << 6;
        const int aoff = (dy * Wp + dx) * 256 + c0;
        const int boff = t * 24576 + c0;          // t*96*256
#pragma unroll
        for (int i = 0; i < 4; ++i)
            gl_lds16(Ac + ag[i] + aoff, lS + i * 2048);
#pragma unroll
        for (int i = 0; i < 4; ++i)
            gl_lds16(Ab + ag[i] + aoff, lS + (4 + i) * 2048);
#pragma unroll
        for (int i = 0; i < 3; ++i)
            gl_lds16(BT + bg[i] + boff, lS + (8 + i) * 2048);
        __syncthreads();
#pragma unroll
        for (int ks = 0; ks < 2; ++ks) {
            const int cO = (((quad + ks * 4) ^ xsw) << 3);
            bf16x8 afc[2], afb[2], bfv[5], bfb;
#pragma unroll
            for (int i = 0; i < 2; ++i) {
                afc[i] = *(const bf16x8*)(Sh + aRow + i * 1024 + cO);
                afb[i] = *(const bf16x8*)(Sh + 8192 + aRow + i * 1024 + cO);
            }
#pragma unroll
            for (int j = 0; j < 5; ++j)
                bfv[j] = *(const bf16x8*)(Sh + 16384 + (j * 16 + l16) * 64 + cO);
            bfb = *(const bf16x8*)(Sh + 16384 + (80 + l16) * 64 + cO);
#pragma unroll
            for (int i = 0; i < 2; ++i) {
#pragma unroll
                for (int j = 0; j < 5; ++j)
                    accC[i][j] = __builtin_amdgcn_mfma_f32_16x16x32_bf16(
                        afc[i], bfv[j], accC[i][j], 0, 0, 0);
                accB[i] = __builtin_amdgcn_mfma_f32_16x16x32_bf16(
                    afb[i], bfb, accB[i], 0, 0, 0);
            }
        }
        __syncthreads();
    }

#pragma unroll
    for (int i = 0; i < 2; ++i) {
#pragma unroll
        for (int r = 0; r < 4; ++r) {
            const int ml  = wv * 32 + i * 16 + quad * 4 + r;
            const int pos = mi + ml;
            const int ob  = (b * 5376 + off_l + pos) * 85;
#pragma unroll
            for (int j = 0; j < 5; ++j)
                out[ob + j * 16 + l16] = accC[i][j][r] + bias[j * 16 + l16];
            if (l16 < 5)
                out[ob + 80 + l16] = accB[i][r] + bias[80 + l16];
        }
    }
}

// ---------------------------------------------------------------------------
// Init: fp32 NCHW -> padded NHWC bf16 via LDS transpose (coalesced both sides)
// One dispatch for all levels; job = b*H + y (one output row).
// ---------------------------------------------------------------------------
__global__ __launch_bounds__(256) void cast_pad_kernel(CastTab tb)
{
    const int bx = blockIdx.x;
    const int l  = (bx >= tb.xend0) + (bx >= tb.xend1);
    const int start = (l == 0) ? 0 : (l == 1 ? tb.xend0 : tb.xend1);
    const int job = bx - start;
    const int H = tb.H[l], lw = tb.lw[l];
    const int W = 1 << lw, Wp = W + 2;
    const int b = job >> lw;               // H == W for all levels
    const int y = job & (W - 1);
    const float* in = tb.in[l] + ((size_t)(b * 256) * H + y) * W;
    bf16* out = tb.out[l] + ((size_t)(b * (H + 2) + y + 1) * Wp + 1) * 256;
    const int tid = threadIdx.x;
    __shared__ bf16 L[16384];              // [x][c], chunk-swizzled by x&31
    const int cpp = 256 >> lw;             // c rows per pass
    const int x = tid & (W - 1);
    const int cb0 = tid >> lw;
    for (int p = 0; p < W; ++p) {
        const int c = p * cpp + cb0;
        float v = in[(size_t)c * H * W + x];
        L[x * 256 + ((((c >> 3) ^ (x & 31))) << 3) + (c & 7)] = (bf16)v;
    }
    __syncthreads();
    const int wpass = W >> 3;
    for (int q = 0; q < wpass; ++q) {
        const int id = q * 256 + tid;
        const int xo = id >> 5;
        const int k  = id & 31;
        bf16x8 vv = *(const bf16x8*)(L + xo * 256 + ((k ^ (xo & 31)) << 3));
        *(bf16x8*)(out + xo * 256 + k * 8) = vv;
    }
}

// zero borders of 5 contiguous padded buffers, all levels in one dispatch
__global__ void border_zero_kernel(BZTab tb)
{
    const int bx = blockIdx.x;
    const int l  = (bx >= tb.xend0) + (bx >= tb.xend1);
    const int start = (l == 0) ? 0 : (l == 1 ? tb.xend0 : tb.xend1);
    const int i   = bx - start;
    const int buf = blockIdx.y;
    const int c   = threadIdx.x;
    const int H = tb.H[l];
    const int ppi = tb.ppi[l];
    const int img = i / ppi;
    const int p   = i - img * ppi;
    const int Wp  = H + 2, Hp = H + 2;
    int y, xp;
    if (p < Wp)            { y = 0;      xp = p; }
    else if (p < 2 * Wp)   { y = Hp - 1; xp = p - Wp; }
    else { int q = p - 2 * Wp; y = 1 + (q >> 1); xp = (q & 1) ? (Wp - 1) : 0; }
    tb.base[l][buf * tb.bufE[l] + ((size_t)(img * Hp + y) * Wp + xp) * 256 + c]
        = (bf16)0.0f;
}

// all weight prepacks in one dispatch:
//  [0,9216) stem cls, [9216,18432) stem box, [18432,19296) pred [t][96][256]
__global__ void prepack_kernel(const float* __restrict__ scw,
                               const float* __restrict__ sbw,
                               const float* __restrict__ pcw,
                               const float* __restrict__ pbw,
                               const float* __restrict__ prw,
                               const float* __restrict__ pcb,
                               const float* __restrict__ pbb,
                               const float* __restrict__ prb,
                               bf16* __restrict__ wc, bf16* __restrict__ wb,
                               bf16* __restrict__ pT, float* __restrict__ pB)
{
    const int ci = threadIdx.x;
    int g = blockIdx.x;
    if (g < 18432) {
        const float* w = (g < 9216) ? scw : sbw;
        bf16* o        = (g < 9216) ? wc  : wb;
        if (g >= 9216) g -= 9216;
        const int co = g & 255;
        const int st = g >> 8;
        const int s  = st / 9;
        const int t  = st - s * 9;
        o[(size_t)g * 256 + ci] = (bf16)w[(((s * 256 + co) * 256 + ci) * 9) + t];
    } else {
        g -= 18432;
        const int t  = g / 96;
        const int co = g - t * 96;
        float v = 0.0f;
        if (co < 80)       v = pcw[((co * 256 + ci) * 9) + t];
        else if (co < 84)  v = pbw[(((co - 80) * 256 + ci) * 9) + t];
        else if (co == 84) v = prw[(ci * 9) + t];
        pT[(size_t)g * 256 + ci] = (bf16)v;
        if (g == 0 && ci < 96) {
            float bvv = 0.0f;
            if (ci < 80)       bvv = pcb[ci];
            else if (ci < 84)  bvv = pbb[ci - 80];
            else if (ci == 84) bvv = prb[0];
            pB[ci] = bvv;
        }
    }
}

// ---------------------------------------------------------------------------
extern "C" void kernel_launch(void* const* d_in, const int* in_sizes, int n_in,
                              void* d_out, int out_size, void* d_ws, size_t ws_size,
                              hipStream_t stream)
{
    (void)in_sizes; (void)n_in; (void)out_size;
    const float* feat[3] = {(const float*)d_in[0], (const float*)d_in[1],
                            (const float*)d_in[2]};
    const float* scw = (const float*)d_in[3];
    const float* scb = (const float*)d_in[4];
    const float* sbw = (const float*)d_in[5];
    const float* sbb = (const float*)d_in[6];
    const float* pcw = (const float*)d_in[7];
    const float* pcb = (const float*)d_in[8];
    const float* pbw = (const float*)d_in[9];
    const float* pbb = (const float*)d_in[10];
    const float* prw = (const float*)d_in[11];
    const float* prb = (const float*)d_in[12];
    float* out = (float*)d_out;

    const int Hs[3]   = {64, 32, 16};
    const int lws[3]  = {6, 5, 4};
    const int lhws[3] = {12, 10, 8};
    const int offl[3] = {0, 4096, 5120};
    const int mtiles[3] = {512, 128, 32};          // M/128 per level
    size_t bufB[3];
    for (int l = 0; l < 3; ++l)
        bufB[l] = (size_t)16 * (Hs[l] + 2) * (Hs[l] + 2) * 256 * 2;

    const size_t WSTEM = (size_t)4 * 9 * 256 * 256 * 2;
    const size_t WPRED = (size_t)9 * 96 * 256 * 2;
    const size_t FULL   = 5 * (bufB[0] + bufB[1] + bufB[2]) + 2 * WSTEM + WPRED + 384;
    const size_t SHARED = 5 * bufB[0] + 2 * WSTEM + WPRED + 384;
    if (ws_size < SHARED) return;
    const bool fused = ws_size >= FULL;

    char* ws = (char*)d_ws;
    bf16* act[3][5];
    size_t off = 0;
    if (fused) {
        for (int l = 0; l < 3; ++l)
            for (int k = 0; k < 5; ++k) { act[l][k] = (bf16*)(ws + off); off += bufB[l]; }
    } else {
        for (int k = 0; k < 5; ++k)
            for (int l = 0; l < 3; ++l) act[l][k] = (bf16*)(ws + (size_t)k * bufB[0]);
        off = 5 * bufB[0];
    }
    bf16*  wbTc = (bf16*)(ws + off); off += WSTEM;
    bf16*  wbTb = (bf16*)(ws + off); off += WSTEM;
    bf16*  pT   = (bf16*)(ws + off); off += WPRED;
    float* pB   = (float*)(ws + off);

    prepack_kernel<<<dim3(19296), 256, 0, stream>>>(scw, sbw, pcw, pbw, prw,
                                                    pcb, pbb, prb,
                                                    wbTc, wbTb, pT, pB);

    auto make_stem_tab = [&](int s, int nlev, const int* levs) {
        StemTab tb{};
        for (int i = 0; i < nlev; ++i) {
            int l = levs[i];
            tb.inC[i]  = (s == 0) ? act[l][0] : ((s & 1) ? act[l][1] : act[l][2]);
            tb.inB[i]  = (s == 0) ? act[l][0] : ((s & 1) ? act[l][3] : act[l][4]);
            tb.outC[i] = (s & 1) ? act[l][2] : act[l][1];
            tb.outB[i] = (s & 1) ? act[l][4] : act[l][3];
            tb.H[i] = Hs[l]; tb.lw[i] = lws[l]; tb.lhw[i] = lhws[l];
        }
        return tb;
    };

    if (fused) {
        // border-zero: one dispatch, all levels x 5 bufs
        BZTab bz{};
        int bpx[3];
        for (int l = 0; l < 3; ++l) {
            bz.base[l] = act[l][0]; bz.H[l] = Hs[l]; bz.bufE[l] = bufB[l] / 2;
            bpx[l] = 2 * (Hs[l] + 2) + 2 * Hs[l];
            bz.ppi[l] = bpx[l];
        }
        bz.xend0 = 16 * bpx[0]; bz.xend1 = bz.xend0 + 16 * bpx[1];
        const int bztot = bz.xend1 + 16 * bpx[2];
        border_zero_kernel<<<dim3(bztot, 5), 256, 0, stream>>>(bz);

        // cast: one dispatch, all levels
        CastTab ct{};
        for (int l = 0; l < 3; ++l) {
            ct.in[l] = feat[l]; ct.out[l] = act[l][0];
            ct.H[l] = Hs[l]; ct.lw[l] = lws[l];
        }
        ct.xend0 = 16 * Hs[0]; ct.xend1 = ct.xend0 + 16 * Hs[1];
        cast_pad_kernel<<<dim3(ct.xend1 + 16 * Hs[2]), 256, 0, stream>>>(ct);

        const int levs[3] = {0, 1, 2};
        const int tx0 = mtiles[0] * 2, tx1 = mtiles[1] * 2, tx2 = mtiles[2] * 2;
        for (int s = 0; s < 4; ++s) {
            StemTab tb = make_stem_tab(s, 3, levs);
            tb.xend0 = tx0; tb.xend1 = tx0 + tx1;
            stem_conv_kernel<<<dim3(tx0 + tx1 + tx2, 1, 2), 256, 0, stream>>>(
                tb, wbTc + (size_t)s * 589824, wbTb + (size_t)s * 589824,
                scb + s * 256, sbb + s * 256);
        }
        PredTab pt{};
        for (int l = 0; l < 3; ++l) {
            pt.inC[l] = act[l][2]; pt.inB[l] = act[l][4];
            pt.H[l] = Hs[l]; pt.lw[l] = lws[l]; pt.lhw[l] = lhws[l]; pt.offl[l] = offl[l];
        }
        pt.xend0 = mtiles[0]; pt.xend1 = mtiles[0] + mtiles[1];
        pred_conv_kernel<<<dim3(mtiles[0] + mtiles[1] + mtiles[2]), 256, 0, stream>>>(
            pt, pT, pB, out);
    } else {
        for (int l = 0; l < 3; ++l) {
            const int bpx = 2 * (Hs[l] + 2) + 2 * Hs[l];
            BZTab bz{};
            bz.base[0] = act[l][0]; bz.H[0] = Hs[l]; bz.bufE[0] = bufB[0] / 2;
            bz.ppi[0] = bpx; bz.xend0 = 16 * bpx; bz.xend1 = 16 * bpx;
            border_zero_kernel<<<dim3(16 * bpx, 5), 256, 0, stream>>>(bz);
            CastTab ct{};
            ct.in[0] = feat[l]; ct.out[0] = act[l][0];
            ct.H[0] = Hs[l]; ct.lw[0] = lws[l];
            ct.xend0 = 16 * Hs[l]; ct.xend1 = 16 * Hs[l];
            cast_pad_kernel<<<dim3(16 * Hs[l]), 256, 0, stream>>>(ct);

            const int levs[1] = {l};
            const int tiles = mtiles[l] * 2;
            for (int s = 0; s < 4; ++s) {
                StemTab tb = make_stem_tab(s, 1, levs);
                tb.xend0 = tiles; tb.xend1 = tiles;
                stem_conv_kernel<<<dim3(tiles, 1, 2), 256, 0, stream>>>(
                    tb, wbTc + (size_t)s * 589824, wbTb + (size_t)s * 589824,
                    scb + s * 256, sbb + s * 256);
            }
            PredTab pt{};
            pt.inC[0] = act[l][2]; pt.inB[0] = act[l][4];
            pt.H[0] = Hs[l]; pt.lw[0] = lws[l]; pt.lhw[0] = lhws[l]; pt.offl[0] = offl[l];
            pt.xend0 = mtiles[l]; pt.xend1 = mtiles[l];
            pred_conv_kernel<<<dim3(mtiles[l]), 256, 0, stream>>>(pt, pT, pB, out);
        }
    }
}